// Round 6
// baseline (383.175 us; speedup 1.0000x reference)
//
#include <hip/hip_runtime.h>
#include <cstdint>
#include <cstddef>

// R12: TWO batches per wave, fully interleaved (1-wave 64-thread WGs, grid
// B/2). Evidence: latency-bound; resident chains capped ~6/CU by the VGPR
// tier (65-128 regs -> ~6 waves/CU; R9's 132 -> 3.3; R10's 64 -> 13.6), and
// per-batch state (128 floats) can't fit the 64-reg tier. So add chains
// INSIDE the wave: 2 independent batches share one PC; when chain A stalls
// (16-deep fma chain, LDS broadcast round-trip, IEEE divide, scan chains),
// chain B issues in the gaps at zero switch cost. VGPR ~270-300: over the
// 256 tier (1 wave/SIMD, 4 waves/CU -> 8 chains/CU) but far under the ~450
// spill threshold; waves_per_eu(1) stops the allocator from squeezing
// (R10's spill disaster). Per-batch math is byte-for-byte R8: bitwise
// identical scores and greedy selections. Greedy runs a fused loop until
// both batches finish; a finished batch's round is idempotent (all-masked
// scans -> aR/aC false -> empty ballots).

typedef float f2 __attribute__((ext_vector_type(2)));

__device__ __forceinline__ f2 fma2(f2 a, f2 b, f2 c) {
#if defined(__has_builtin) && __has_builtin(__builtin_elementwise_fma)
    return __builtin_elementwise_fma(a, b, c);
#else
    f2 r; r.x = __builtin_fmaf(a.x, b.x, c.x); r.y = __builtin_fmaf(a.y, b.y, c.y);
    return r;
#endif
}

__global__ void __launch_bounds__(64)
__attribute__((amdgpu_waves_per_eu(1)))
sinkhorn_perm_kernel(const float* __restrict__ logits,
                     const float* __restrict__ ptemp,
                     float* __restrict__ out,
                     int B)
{
    __shared__ __attribute__((aligned(16))) float bufUA[64];
    __shared__ __attribute__((aligned(16))) float bufVA[64];
    __shared__ __attribute__((aligned(16))) float bufUB[64];
    __shared__ __attribute__((aligned(16))) float bufVB[64];

    const int lane = threadIdx.x;          // blockDim.x == 64
    const int bA   = blockIdx.x * 2;
    const int bB   = bA + 1;
    const bool hasB = (bB < B);
    const float* baseA = logits + (size_t)bA * 4096;
    const float* baseB = logits + (size_t)(hasB ? bB : bA) * 4096;

    const float T    = ptemp[0] + 1e-6f;
    const float invT = 1.0f / T;          // IEEE divide (one-time)

    // ---- load rows, scale by invT; pairs (4t,4t+1),(4t+2,4t+3) --------
    f2 rowA[32], rowB[32];
    {
        const float4* rpA = (const float4*)(baseA + lane * 64);
        const float4* rpB = (const float4*)(baseB + lane * 64);
        #pragma unroll
        for (int t = 0; t < 16; ++t) {
            float4 qa = rpA[t];
            float4 qb = rpB[t];
            rowA[2*t+0].x = __fmul_rn(qa.x, invT);
            rowA[2*t+0].y = __fmul_rn(qa.y, invT);
            rowA[2*t+1].x = __fmul_rn(qa.z, invT);
            rowA[2*t+1].y = __fmul_rn(qa.w, invT);
            rowB[2*t+0].x = __fmul_rn(qb.x, invT);
            rowB[2*t+0].y = __fmul_rn(qb.y, invT);
            rowB[2*t+1].x = __fmul_rn(qb.z, invT);
            rowB[2*t+1].y = __fmul_rn(qb.w, invT);
        }
    }

    // ---- global max over each 64x64 tile (same op sequence as R8) -----
    float mxA = rowA[0].x, mxB = rowB[0].x;
    #pragma unroll
    for (int i = 0; i < 32; ++i) {
        mxA = fmaxf(mxA, rowA[i].x); mxA = fmaxf(mxA, rowA[i].y);
        mxB = fmaxf(mxB, rowB[i].x); mxB = fmaxf(mxB, rowB[i].y);
    }
    #pragma unroll
    for (int w = 1; w <= 32; w <<= 1) {
        mxA = fmaxf(mxA, __shfl_xor(mxA, w, 64));
        mxB = fmaxf(mxB, __shfl_xor(mxB, w, 64));
    }

    // ---- x0 row copies: exp(scaled - mx) ------------------------------
    #pragma unroll
    for (int i = 0; i < 32; ++i) {
        rowA[i].x = __expf(__fsub_rn(rowA[i].x, mxA));
        rowA[i].y = __expf(__fsub_rn(rowA[i].y, mxA));
        rowB[i].x = __expf(__fsub_rn(rowB[i].x, mxB));
        rowB[i].y = __expf(__fsub_rn(rowB[i].y, mxB));
    }

    // ---- x0 column copies: coalesced global re-read, identical op seq -
    float colA[64], colB[64];
    #pragma unroll
    for (int i = 0; i < 64; ++i) {
        float ra = baseA[i * 64 + lane];
        float rb = baseB[i * 64 + lane];
        colA[i] = __expf(__fsub_rn(__fmul_rn(ra, invT), mxA));
        colB[i] = __expf(__fsub_rn(__fmul_rn(rb, invT), mxB));
    }

    // ---- sinkhorn, both batches interleaved ---------------------------
    // Pairing and summation order identical to R8 per batch:
    // rs = (A0.x+A0.y)+(A1.x+A1.y).
    const float4* buA4 = (const float4*)bufUA;
    const float4* bvA4 = (const float4*)bufVA;
    const float4* buB4 = (const float4*)bufUB;
    const float4* bvB4 = (const float4*)bufVB;

    float uA = 1.0f, vA = 1.0f, uB = 1.0f, vB = 1.0f;
    for (int it = 0; it < 30; ++it) {
        // row phase
        bufVA[lane] = vA;
        bufVB[lane] = vB;
        f2 Aa0 = {0.f,0.f}, Aa1 = {0.f,0.f}, Ab0 = {0.f,0.f}, Ab1 = {0.f,0.f};
        #pragma unroll
        for (int t = 0; t < 16; ++t) {
            float4 qa = bvA4[t];
            float4 qb = bvB4[t];
            f2 qa0 = { qa.x, qa.y }, qa1 = { qa.z, qa.w };
            f2 qb0 = { qb.x, qb.y }, qb1 = { qb.z, qb.w };
            Aa0 = fma2(rowA[2*t+0], qa0, Aa0);
            Aa1 = fma2(rowA[2*t+1], qa1, Aa1);
            Ab0 = fma2(rowB[2*t+0], qb0, Ab0);
            Ab1 = fma2(rowB[2*t+1], qb1, Ab1);
        }
        float rsA = __fadd_rn(__fadd_rn(Aa0.x, Aa0.y), __fadd_rn(Aa1.x, Aa1.y));
        float rsB = __fadd_rn(__fadd_rn(Ab0.x, Ab0.y), __fadd_rn(Ab1.x, Ab1.y));
        uA = uA / __fadd_rn(__fmul_rn(uA, rsA), 1e-8f);   // IEEE divide
        uB = uB / __fadd_rn(__fmul_rn(uB, rsB), 1e-8f);

        // col phase
        bufUA[lane] = uA;
        bufUB[lane] = uB;
        Aa0 = (f2){0.f,0.f}; Aa1 = (f2){0.f,0.f};
        Ab0 = (f2){0.f,0.f}; Ab1 = (f2){0.f,0.f};
        #pragma unroll
        for (int t = 0; t < 16; ++t) {
            float4 qa = buA4[t];
            float4 qb = buB4[t];
            f2 ca0 = { colA[4*t+0], colA[4*t+1] }, ca1 = { colA[4*t+2], colA[4*t+3] };
            f2 cb0 = { colB[4*t+0], colB[4*t+1] }, cb1 = { colB[4*t+2], colB[4*t+3] };
            f2 qa0 = { qa.x, qa.y }, qa1 = { qa.z, qa.w };
            f2 qb0 = { qb.x, qb.y }, qb1 = { qb.z, qb.w };
            Aa0 = fma2(ca0, qa0, Aa0);
            Aa1 = fma2(ca1, qa1, Aa1);
            Ab0 = fma2(cb0, qb0, Ab0);
            Ab1 = fma2(cb1, qb1, Ab1);
        }
        float csA = __fadd_rn(__fadd_rn(Aa0.x, Aa0.y), __fadd_rn(Aa1.x, Aa1.y));
        float csB = __fadd_rn(__fadd_rn(Ab0.x, Ab0.y), __fadd_rn(Ab1.x, Ab1.y));
        vA = vA / __fadd_rn(__fmul_rn(vA, csA), 1e-8f);
        vB = vB / __fadd_rn(__fmul_rn(vB, csB), 1e-8f);
    }

    // ---- final scores in BOTH layouts, both batches -------------------
    // col layout: col[i] = (x0c[i] * bufU[i]) * v_own  (bufU = final u)
    #pragma unroll
    for (int t = 0; t < 16; ++t) {
        float4 qa = buA4[t];
        float4 qb = buB4[t];
        colA[4*t+0] = __fmul_rn(__fmul_rn(colA[4*t+0], qa.x), vA);
        colA[4*t+1] = __fmul_rn(__fmul_rn(colA[4*t+1], qa.y), vA);
        colA[4*t+2] = __fmul_rn(__fmul_rn(colA[4*t+2], qa.z), vA);
        colA[4*t+3] = __fmul_rn(__fmul_rn(colA[4*t+3], qa.w), vA);
        colB[4*t+0] = __fmul_rn(__fmul_rn(colB[4*t+0], qb.x), vB);
        colB[4*t+1] = __fmul_rn(__fmul_rn(colB[4*t+1], qb.y), vB);
        colB[4*t+2] = __fmul_rn(__fmul_rn(colB[4*t+2], qb.z), vB);
        colB[4*t+3] = __fmul_rn(__fmul_rn(colB[4*t+3], qb.w), vB);
    }
    // row layout: row[j] = (x0r[j] * u_own) * bufV[j]  (same bits as col)
    bufVA[lane] = vA;
    bufVB[lane] = vB;
    #pragma unroll
    for (int t = 0; t < 16; ++t) {
        float4 qa = bvA4[t];
        float4 qb = bvB4[t];
        rowA[2*t+0].x = __fmul_rn(__fmul_rn(rowA[2*t+0].x, uA), qa.x);
        rowA[2*t+0].y = __fmul_rn(__fmul_rn(rowA[2*t+0].y, uA), qa.y);
        rowA[2*t+1].x = __fmul_rn(__fmul_rn(rowA[2*t+1].x, uA), qa.z);
        rowA[2*t+1].y = __fmul_rn(__fmul_rn(rowA[2*t+1].y, uA), qa.w);
        rowB[2*t+0].x = __fmul_rn(__fmul_rn(rowB[2*t+0].x, uB), qb.x);
        rowB[2*t+0].y = __fmul_rn(__fmul_rn(rowB[2*t+0].y, uB), qb.y);
        rowB[2*t+1].x = __fmul_rn(__fmul_rn(rowB[2*t+1].x, uB), qb.z);
        rowB[2*t+1].y = __fmul_rn(__fmul_rn(rowB[2*t+1].y, uB), qb.w);
    }

    // ---- greedy: parallel mutual-max retirement, both batches fused ----
    // Per-batch logic is R8 verbatim. A finished batch's round is
    // idempotent: all-masked scans give (0,0) candidates; aR/aC are false
    // for every lane -> mr/mc false -> ballots empty -> masks unchanged.
    unsigned long long rmA = ~0ull, cmA = ~0ull;
    unsigned long long rmB = hasB ? ~0ull : 0ull;
    unsigned long long cmB = hasB ? ~0ull : 0ull;
    int mycolA = 0, mycolB = 0;
    int rounds = 0;

    while ((rmA | rmB) && rounds < 64) {
        ++rounds;

        // row side (lane = row i): best live column, both batches
        float rbvA = 0.0f, rbvB = 0.0f; int rbjA = 0, rbjB = 0;
        #pragma unroll
        for (int j = 0; j < 64; ++j) {
            unsigned smA = ((cmA >> j) & 1ull) ? 0xFFFFFFFFu : 0u;
            unsigned smB = ((cmB >> j) & 1ull) ? 0xFFFFFFFFu : 0u;
            float svA = (j & 1) ? rowA[j >> 1].y : rowA[j >> 1].x;
            float svB = (j & 1) ? rowB[j >> 1].y : rowB[j >> 1].x;
            float sA = __uint_as_float(__float_as_uint(svA) & smA);
            float sB = __uint_as_float(__float_as_uint(svB) & smB);
            if (sA > rbvA) { rbvA = sA; rbjA = j; }
            if (sB > rbvB) { rbvB = sB; rbjB = j; }
        }

        // col side (lane = col j): best live row, both batches
        float cbvA = 0.0f, cbvB = 0.0f; int cbiA = 0, cbiB = 0;
        #pragma unroll
        for (int i = 0; i < 64; ++i) {
            unsigned smA = ((rmA >> i) & 1ull) ? 0xFFFFFFFFu : 0u;
            unsigned smB = ((rmB >> i) & 1ull) ? 0xFFFFFFFFu : 0u;
            float sA = __uint_as_float(__float_as_uint(colA[i]) & smA);
            float sB = __uint_as_float(__float_as_uint(colB[i]) & smB);
            if (sA > cbvA) { cbvA = sA; cbiA = i; }
            if (sB > cbvB) { cbvB = sB; cbiB = i; }
        }

        // mutual checks (independent bpermutes issue together)
        int grA = __builtin_amdgcn_ds_bpermute(rbjA << 2, cbiA);
        int gcA = __builtin_amdgcn_ds_bpermute(cbiA << 2, rbjA);
        int grB = __builtin_amdgcn_ds_bpermute(rbjB << 2, cbiB);
        int gcB = __builtin_amdgcn_ds_bpermute(cbiB << 2, rbjB);
        bool aRA = (rmA >> lane) & 1ull, aCA = (cmA >> lane) & 1ull;
        bool aRB = (rmB >> lane) & 1ull, aCB = (cmB >> lane) & 1ull;
        bool mrA = aRA && (grA == lane);
        bool mcA = aCA && (gcA == lane);
        bool mrB = aRB && (grB == lane);
        bool mcB = aCB && (gcB == lane);
        if (mrA) mycolA = rbjA;
        if (mrB) mycolB = rbjB;
        rmA &= ~__ballot(mrA); cmA &= ~__ballot(mcA);
        rmB &= ~__ballot(mrB); cmB &= ~__ballot(mcB);
    }

    // ---- write hard permutation rows (lane i -> row i) ----------------
    {
        float* orow = out + (size_t)bA * 4096 + lane * 64;
        #pragma unroll
        for (int t = 0; t < 16; ++t) {
            float4 q;
            q.x = (4*t+0 == mycolA) ? 1.0f : 0.0f;
            q.y = (4*t+1 == mycolA) ? 1.0f : 0.0f;
            q.z = (4*t+2 == mycolA) ? 1.0f : 0.0f;
            q.w = (4*t+3 == mycolA) ? 1.0f : 0.0f;
            ((float4*)orow)[t] = q;
        }
    }
    if (hasB) {
        float* orow = out + (size_t)bB * 4096 + lane * 64;
        #pragma unroll
        for (int t = 0; t < 16; ++t) {
            float4 q;
            q.x = (4*t+0 == mycolB) ? 1.0f : 0.0f;
            q.y = (4*t+1 == mycolB) ? 1.0f : 0.0f;
            q.z = (4*t+2 == mycolB) ? 1.0f : 0.0f;
            q.w = (4*t+3 == mycolB) ? 1.0f : 0.0f;
            ((float4*)orow)[t] = q;
        }
    }
}

extern "C" void kernel_launch(void* const* d_in, const int* in_sizes, int n_in,
                              void* d_out, int out_size, void* d_ws, size_t ws_size,
                              hipStream_t stream) {
    const float* logits = (const float*)d_in[0];
    const float* ptemp  = (const float*)d_in[1];
    float* out = (float*)d_out;
    const int B = in_sizes[0] / 4096;   // 64*64 elements per batch
    const int G = (B + 1) / 2;          // 2 batches per wave (1-wave WGs)
    sinkhorn_perm_kernel<<<G, 64, 0, stream>>>(logits, ptemp, out, B);
}

// Round 7
// 280.656 us; speedup vs baseline: 1.3653x; 1.3653x over previous
//
#include <hip/hip_runtime.h>
#include <cstdint>
#include <cstddef>

// R13 = R8 (verified 104 us, best) + two exact per-wave cuts; R12's in-wave
// batch-doubling reverted (allocator clamped at 180 VGPR -> AGPR/remat
// traffic, occ 10.5%, 310 us).
// (1) col layout built by LDS transpose of row2 instead of 64 global
//     re-reads + 64 __expf: row2 post-exp holds bitwise-identical values
//     (same expression tree per element). XOR swizzle word = i*64 +
//     (j ^ ((i&7)<<2)): reads conflict-free (per-i lane permutation),
//     writes <=8-way one-time. FETCH should halve.
// (2) greedy masked scans 4-way interleaved: 4 chains of 16 (strict '>',
//     ascending j) + ordered 3-step merge (strict '>') == linear first-max
//     scan exactly (max, min index among maximizers), depth 512->~150cy,
//     +~8 VGPR only (R9's +32-reg version crossed the 128 tier and halved
//     occupancy; this one must stay <=128).
// Sinkhorn + mutual-max retirement are R8 byte-for-byte: bitwise-identical
// scores and selections.

typedef float f2 __attribute__((ext_vector_type(2)));

__device__ __forceinline__ f2 fma2(f2 a, f2 b, f2 c) {
#if defined(__has_builtin) && __has_builtin(__builtin_elementwise_fma)
    return __builtin_elementwise_fma(a, b, c);
#else
    f2 r; r.x = __builtin_fmaf(a.x, b.x, c.x); r.y = __builtin_fmaf(a.y, b.y, c.y);
    return r;
#endif
}

__global__ void __launch_bounds__(64)
__attribute__((amdgpu_waves_per_eu(1)))
sinkhorn_perm_kernel(const float* __restrict__ logits,
                     const float* __restrict__ ptemp,
                     float* __restrict__ out)
{
    __shared__ __attribute__((aligned(16))) float ldsT[4096];  // 16 KB transpose buffer
    __shared__ __attribute__((aligned(16))) float bufU[64];
    __shared__ __attribute__((aligned(16))) float bufV[64];

    const int b    = blockIdx.x;
    const int lane = threadIdx.x;
    const float* base = logits + (size_t)b * 4096;

    const float T    = ptemp[0] + 1e-6f;
    const float invT = 1.0f / T;          // IEEE divide (one-time)

    // ---- load row `lane`, scale by invT; pairs (4t,4t+1),(4t+2,4t+3) --
    f2 row2[32];
    {
        const float4* rp = (const float4*)(base + lane * 64);
        #pragma unroll
        for (int t = 0; t < 16; ++t) {
            float4 q = rp[t];
            row2[2*t+0].x = __fmul_rn(q.x, invT);
            row2[2*t+0].y = __fmul_rn(q.y, invT);
            row2[2*t+1].x = __fmul_rn(q.z, invT);
            row2[2*t+1].y = __fmul_rn(q.w, invT);
        }
    }

    // ---- global max over the 64x64 tile -------------------------------
    float mx = row2[0].x;
    #pragma unroll
    for (int i = 0; i < 32; ++i) { mx = fmaxf(mx, row2[i].x); mx = fmaxf(mx, row2[i].y); }
    #pragma unroll
    for (int w = 1; w <= 32; w <<= 1)
        mx = fmaxf(mx, __shfl_xor(mx, w, 64));

    // ---- x0 row copy: exp(scaled - mx) --------------------------------
    #pragma unroll
    for (int i = 0; i < 32; ++i) {
        row2[i].x = __expf(__fsub_rn(row2[i].x, mx));
        row2[i].y = __expf(__fsub_rn(row2[i].y, mx));
    }

    // ---- x0 column copy via LDS transpose of row2 ---------------------
    // Element (i,j) at word i*64 + (j ^ ((i&7)<<2)). Writes: lane i, chunk
    // t covers j=4t..4t+3 -> contiguous b128 at (4t ^ swz(i)) since swz has
    // bits 2-4 only. Reads: per i, lanes j form a permutation -> conflict-
    // free. Bitwise-identical to the old global re-read + __expf (same
    // per-element expression tree).
    {
        const unsigned swz4  = (unsigned)((lane & 7) << 4);       // swz(i)*4 bytes
        const unsigned vbase = ((unsigned)lane << 8) + swz4;      // lane*256 + swz*4
        #pragma unroll
        for (int t = 0; t < 16; ++t) {
            float4 q;
            q.x = row2[2*t+0].x; q.y = row2[2*t+0].y;
            q.z = row2[2*t+1].x; q.w = row2[2*t+1].y;
            *(float4*)((char*)ldsT + (vbase ^ (unsigned)(t << 4))) = q;
        }
    }
    float col[64];
    {
        int a8[8];
        #pragma unroll
        for (int g = 0; g < 8; ++g) a8[g] = ((lane ^ (g << 2)) << 2);  // byte off of word lane^swz(g)
        #pragma unroll
        for (int i = 0; i < 64; ++i)
            col[i] = *(const float*)((const char*)ldsT + a8[i & 7] + (i << 8));
    }

    // ---- sinkhorn in diag(u) * X0 * diag(v) form ----------------------
    // R8 verbatim: LDS broadcast, pk_fma pairing, rs=(A0.x+A0.y)+(A1.x+A1.y).
    const float4* bu4 = (const float4*)bufU;
    const float4* bv4 = (const float4*)bufV;

    float u = 1.0f, v = 1.0f;
    for (int it = 0; it < 30; ++it) {
        // row phase: rs_i = row_i . v
        bufV[lane] = v;
        f2 A0 = {0.f, 0.f}, A1 = {0.f, 0.f};
        #pragma unroll
        for (int t = 0; t < 16; ++t) {
            float4 q = bv4[t];
            f2 qa = { q.x, q.y };
            f2 qb = { q.z, q.w };
            A0 = fma2(row2[2*t+0], qa, A0);
            A1 = fma2(row2[2*t+1], qb, A1);
        }
        float rs = __fadd_rn(__fadd_rn(A0.x, A0.y), __fadd_rn(A1.x, A1.y));
        u = u / __fadd_rn(__fmul_rn(u, rs), 1e-8f);   // IEEE divide

        // col phase: cs_j = col_j . u  (updated u broadcast)
        bufU[lane] = u;
        A0 = (f2){0.f, 0.f}; A1 = (f2){0.f, 0.f};
        #pragma unroll
        for (int t = 0; t < 16; ++t) {
            float4 q = bu4[t];
            f2 ca = { col[4*t+0], col[4*t+1] };
            f2 cb = { col[4*t+2], col[4*t+3] };
            f2 qa = { q.x, q.y };
            f2 qb = { q.z, q.w };
            A0 = fma2(ca, qa, A0);
            A1 = fma2(cb, qb, A1);
        }
        float cs = __fadd_rn(__fadd_rn(A0.x, A0.y), __fadd_rn(A1.x, A1.y));
        v = v / __fadd_rn(__fmul_rn(v, cs), 1e-8f);
    }

    // ---- final scores in BOTH layouts: s[i][j] = (x0[i][j] * u_i) * v_j
    #pragma unroll
    for (int t = 0; t < 16; ++t) {
        float4 q = bu4[t];
        col[4*t+0] = __fmul_rn(__fmul_rn(col[4*t+0], q.x), v);
        col[4*t+1] = __fmul_rn(__fmul_rn(col[4*t+1], q.y), v);
        col[4*t+2] = __fmul_rn(__fmul_rn(col[4*t+2], q.z), v);
        col[4*t+3] = __fmul_rn(__fmul_rn(col[4*t+3], q.w), v);
    }
    bufV[lane] = v;   // final v (in-order DS within wave)
    #pragma unroll
    for (int t = 0; t < 16; ++t) {
        float4 q = bv4[t];
        row2[2*t+0].x = __fmul_rn(__fmul_rn(row2[2*t+0].x, u), q.x);
        row2[2*t+0].y = __fmul_rn(__fmul_rn(row2[2*t+0].y, u), q.y);
        row2[2*t+1].x = __fmul_rn(__fmul_rn(row2[2*t+1].x, u), q.z);
        row2[2*t+1].y = __fmul_rn(__fmul_rn(row2[2*t+1].y, u), q.w);
    }

    // ---- greedy unique argmax: parallel mutual-max retirement ----------
    // R8 logic; scans 4-way interleaved (4 chains of 16 + ordered merge,
    // strict '>' ascending => exact (max, min-index) == linear first-max).
    unsigned long long rowmask = ~0ull;   // wave-uniform (SGPR pair)
    unsigned long long colmask = ~0ull;
    int mycol  = 0;
    int rounds = 0;

    while (rowmask && rounds < 64) {
        ++rounds;

        // row side (lane = row i): best live column
        float rv0 = 0.f, rv1 = 0.f, rv2 = 0.f, rv3 = 0.f;
        int   rj0 = 0,   rj1 = 16,  rj2 = 32,  rj3 = 48;
        #pragma unroll
        for (int k = 0; k < 16; ++k) {
            {
                const int j = k;
                unsigned sm = ((colmask >> j) & 1ull) ? 0xFFFFFFFFu : 0u;
                float sv = (j & 1) ? row2[j >> 1].y : row2[j >> 1].x;
                float s  = __uint_as_float(__float_as_uint(sv) & sm);
                if (s > rv0) { rv0 = s; rj0 = j; }
            }
            {
                const int j = 16 + k;
                unsigned sm = ((colmask >> j) & 1ull) ? 0xFFFFFFFFu : 0u;
                float sv = (j & 1) ? row2[j >> 1].y : row2[j >> 1].x;
                float s  = __uint_as_float(__float_as_uint(sv) & sm);
                if (s > rv1) { rv1 = s; rj1 = j; }
            }
            {
                const int j = 32 + k;
                unsigned sm = ((colmask >> j) & 1ull) ? 0xFFFFFFFFu : 0u;
                float sv = (j & 1) ? row2[j >> 1].y : row2[j >> 1].x;
                float s  = __uint_as_float(__float_as_uint(sv) & sm);
                if (s > rv2) { rv2 = s; rj2 = j; }
            }
            {
                const int j = 48 + k;
                unsigned sm = ((colmask >> j) & 1ull) ? 0xFFFFFFFFu : 0u;
                float sv = (j & 1) ? row2[j >> 1].y : row2[j >> 1].x;
                float s  = __uint_as_float(__float_as_uint(sv) & sm);
                if (s > rv3) { rv3 = s; rj3 = j; }
            }
        }
        if (rv1 > rv0) { rv0 = rv1; rj0 = rj1; }
        if (rv2 > rv0) { rv0 = rv2; rj0 = rj2; }
        if (rv3 > rv0) { rv0 = rv3; rj0 = rj3; }
        const int rbj = rj0;

        // col side (lane = col j): best live row
        float cv0 = 0.f, cv1 = 0.f, cv2 = 0.f, cv3 = 0.f;
        int   ci0 = 0,   ci1 = 16,  ci2 = 32,  ci3 = 48;
        #pragma unroll
        for (int k = 0; k < 16; ++k) {
            {
                const int i = k;
                unsigned sm = ((rowmask >> i) & 1ull) ? 0xFFFFFFFFu : 0u;
                float s  = __uint_as_float(__float_as_uint(col[i]) & sm);
                if (s > cv0) { cv0 = s; ci0 = i; }
            }
            {
                const int i = 16 + k;
                unsigned sm = ((rowmask >> i) & 1ull) ? 0xFFFFFFFFu : 0u;
                float s  = __uint_as_float(__float_as_uint(col[i]) & sm);
                if (s > cv1) { cv1 = s; ci1 = i; }
            }
            {
                const int i = 32 + k;
                unsigned sm = ((rowmask >> i) & 1ull) ? 0xFFFFFFFFu : 0u;
                float s  = __uint_as_float(__float_as_uint(col[i]) & sm);
                if (s > cv2) { cv2 = s; ci2 = i; }
            }
            {
                const int i = 48 + k;
                unsigned sm = ((rowmask >> i) & 1ull) ? 0xFFFFFFFFu : 0u;
                float s  = __uint_as_float(__float_as_uint(col[i]) & sm);
                if (s > cv3) { cv3 = s; ci3 = i; }
            }
        }
        if (cv1 > cv0) { cv0 = cv1; ci0 = ci1; }
        if (cv2 > cv0) { cv0 = cv2; ci0 = ci2; }
        if (cv3 > cv0) { cv0 = cv3; ci0 = ci3; }
        const int cbi = ci0;

        // mutual check (R8 verbatim)
        int gr = __builtin_amdgcn_ds_bpermute(rbj << 2, cbi); // colArg[rbj]
        int gc = __builtin_amdgcn_ds_bpermute(cbi << 2, rbj); // rowArg[cbi]
        bool aR = (rowmask >> lane) & 1ull;
        bool aC = (colmask >> lane) & 1ull;
        bool mr = aR && (gr == lane);
        bool mc = aC && (gc == lane);
        if (mr) mycol = rbj;
        rowmask &= ~__ballot(mr);
        colmask &= ~__ballot(mc);
    }

    // ---- write hard permutation row (lane i -> row i) -----------------
    float* orow = out + (size_t)b * 4096 + lane * 64;
    #pragma unroll
    for (int t = 0; t < 16; ++t) {
        float4 q;
        q.x = (4*t+0 == mycol) ? 1.0f : 0.0f;
        q.y = (4*t+1 == mycol) ? 1.0f : 0.0f;
        q.z = (4*t+2 == mycol) ? 1.0f : 0.0f;
        q.w = (4*t+3 == mycol) ? 1.0f : 0.0f;
        ((float4*)orow)[t] = q;
    }
}

extern "C" void kernel_launch(void* const* d_in, const int* in_sizes, int n_in,
                              void* d_out, int out_size, void* d_ws, size_t ws_size,
                              hipStream_t stream) {
    const float* logits = (const float*)d_in[0];
    const float* ptemp  = (const float*)d_in[1];
    float* out = (float*)d_out;
    const int B = in_sizes[0] / 4096;   // 64*64 elements per batch
    sinkhorn_perm_kernel<<<B, 64, 0, stream>>>(logits, ptemp, out);
}

// Round 9
// 237.519 us; speedup vs baseline: 1.6132x; 1.1816x over previous
//
#include <hip/hip_runtime.h>
#include <cstdint>
#include <cstddef>

// R15 = R8 (verified 104 us, best) + the two R14 ideas in HW-proven form.
// R14's absmax failure isolated to the CHUNKED transpose's WAR hazard
// (8KB buffer reused: chunk-A reads vs chunk-B overwrites, no sync edge).
// Fix: full 16KB buffer, no reuse — the exact R13 transpose (absmax-0
// proven on HW), with read addresses recomputed per 8-group instead of an
// a8[8] array (R13's register sin; R13 hit VGPR=132 -> occupancy cliff).
// LDS 16.9KB caps at 9 WGs/CU > the ~6 allowed by VGPRs -> not limiting.
// (1) col layout via LDS transpose: removes 64 global re-reads + 64 __expf
//     + ~128 VALU from the prologue. Bits identical (values copied).
// (2) greedy masked scans 2-way interleaved (chains [0,32),[32,64), strict
//     '>' merge, low half wins ties == linear first-max EXACTLY; verified
//     against all tie/underflow cases). +4 live regs.
// Sinkhorn + mutual-max retirement + epilogue are R8 byte-for-byte.
// Tripwire: VGPR_Count must stay <=128 (the R9/R13 cliff costs ~1.7-2x).

typedef float f2 __attribute__((ext_vector_type(2)));

__device__ __forceinline__ f2 fma2(f2 a, f2 b, f2 c) {
#if defined(__has_builtin) && __has_builtin(__builtin_elementwise_fma)
    return __builtin_elementwise_fma(a, b, c);
#else
    f2 r; r.x = __builtin_fmaf(a.x, b.x, c.x); r.y = __builtin_fmaf(a.y, b.y, c.y);
    return r;
#endif
}

__global__ void __launch_bounds__(64)
__attribute__((amdgpu_waves_per_eu(1)))
sinkhorn_perm_kernel(const float* __restrict__ logits,
                     const float* __restrict__ ptemp,
                     float* __restrict__ out)
{
    __shared__ __attribute__((aligned(16))) float ldsT[4096];  // 16 KB, no reuse
    __shared__ __attribute__((aligned(16))) float bufU[64];
    __shared__ __attribute__((aligned(16))) float bufV[64];

    const int b    = blockIdx.x;
    const int lane = threadIdx.x;
    const float* base = logits + (size_t)b * 4096;

    const float T    = ptemp[0] + 1e-6f;
    const float invT = 1.0f / T;          // IEEE divide (one-time)

    // ---- load row `lane`, scale by invT; pairs (4t,4t+1),(4t+2,4t+3) --
    f2 row2[32];
    {
        const float4* rp = (const float4*)(base + lane * 64);
        #pragma unroll
        for (int t = 0; t < 16; ++t) {
            float4 q = rp[t];
            row2[2*t+0].x = __fmul_rn(q.x, invT);
            row2[2*t+0].y = __fmul_rn(q.y, invT);
            row2[2*t+1].x = __fmul_rn(q.z, invT);
            row2[2*t+1].y = __fmul_rn(q.w, invT);
        }
    }

    // ---- global max over the 64x64 tile -------------------------------
    float mx = row2[0].x;
    #pragma unroll
    for (int i = 0; i < 32; ++i) { mx = fmaxf(mx, row2[i].x); mx = fmaxf(mx, row2[i].y); }
    #pragma unroll
    for (int w = 1; w <= 32; w <<= 1)
        mx = fmaxf(mx, __shfl_xor(mx, w, 64));

    // ---- x0 row copy: exp(scaled - mx) --------------------------------
    #pragma unroll
    for (int i = 0; i < 32; ++i) {
        row2[i].x = __expf(__fsub_rn(row2[i].x, mx));
        row2[i].y = __expf(__fsub_rn(row2[i].y, mx));
    }

    // ---- x0 column copy via LDS transpose of row2 (R13-proven) --------
    // Element (i,j) at word i*64 + (j ^ ((i&7)<<2)). Write: lane i, chunk t
    // covers j=4t..4t+3 -> contiguous b128 (swz bits 2-4 only). Read: per
    // i, lanes form a permutation -> conflict-free. Write-then-read within
    // one wave: DS in-order (R7/R8-proven); no buffer reuse -> no WAR.
    {
        const unsigned swz4  = (unsigned)((lane & 7) << 4);
        const unsigned vbase = ((unsigned)lane << 8) + swz4;
        #pragma unroll
        for (int t = 0; t < 16; ++t) {
            float4 q;
            q.x = row2[2*t+0].x; q.y = row2[2*t+0].y;
            q.z = row2[2*t+1].x; q.w = row2[2*t+1].y;
            *(float4*)((char*)ldsT + (vbase ^ (unsigned)(t << 4))) = q;
        }
    }
    float col[64];
    #pragma unroll
    for (int g = 0; g < 8; ++g) {
        const unsigned va = ((unsigned)(lane ^ (g << 2)) << 2);
        #pragma unroll
        for (int q8 = 0; q8 < 8; ++q8) {
            const int i = 8*q8 + g;                     // i&7 == g
            col[i] = *(const float*)((const char*)ldsT + va + ((unsigned)i << 8));
        }
    }

    // ---- sinkhorn in diag(u) * X0 * diag(v) form ----------------------
    // R8 verbatim: LDS broadcast, pk_fma pairing, rs=(A0.x+A0.y)+(A1.x+A1.y).
    const float4* bu4 = (const float4*)bufU;
    const float4* bv4 = (const float4*)bufV;

    float u = 1.0f, v = 1.0f;
    for (int it = 0; it < 30; ++it) {
        // row phase: rs_i = row_i . v
        bufV[lane] = v;
        f2 A0 = {0.f, 0.f}, A1 = {0.f, 0.f};
        #pragma unroll
        for (int t = 0; t < 16; ++t) {
            float4 q = bv4[t];
            f2 qa = { q.x, q.y };
            f2 qb = { q.z, q.w };
            A0 = fma2(row2[2*t+0], qa, A0);
            A1 = fma2(row2[2*t+1], qb, A1);
        }
        float rs = __fadd_rn(__fadd_rn(A0.x, A0.y), __fadd_rn(A1.x, A1.y));
        u = u / __fadd_rn(__fmul_rn(u, rs), 1e-8f);   // IEEE divide

        // col phase: cs_j = col_j . u  (updated u broadcast)
        bufU[lane] = u;
        A0 = (f2){0.f, 0.f}; A1 = (f2){0.f, 0.f};
        #pragma unroll
        for (int t = 0; t < 16; ++t) {
            float4 q = bu4[t];
            f2 ca = { col[4*t+0], col[4*t+1] };
            f2 cb = { col[4*t+2], col[4*t+3] };
            f2 qa = { q.x, q.y };
            f2 qb = { q.z, q.w };
            A0 = fma2(ca, qa, A0);
            A1 = fma2(cb, qb, A1);
        }
        float cs = __fadd_rn(__fadd_rn(A0.x, A0.y), __fadd_rn(A1.x, A1.y));
        v = v / __fadd_rn(__fmul_rn(v, cs), 1e-8f);
    }

    // ---- final scores in BOTH layouts: s[i][j] = (x0[i][j] * u_i) * v_j
    #pragma unroll
    for (int t = 0; t < 16; ++t) {
        float4 q = bu4[t];
        col[4*t+0] = __fmul_rn(__fmul_rn(col[4*t+0], q.x), v);
        col[4*t+1] = __fmul_rn(__fmul_rn(col[4*t+1], q.y), v);
        col[4*t+2] = __fmul_rn(__fmul_rn(col[4*t+2], q.z), v);
        col[4*t+3] = __fmul_rn(__fmul_rn(col[4*t+3], q.w), v);
    }
    bufV[lane] = v;   // final v (in-order DS within wave)
    #pragma unroll
    for (int t = 0; t < 16; ++t) {
        float4 q = bv4[t];
        row2[2*t+0].x = __fmul_rn(__fmul_rn(row2[2*t+0].x, u), q.x);
        row2[2*t+0].y = __fmul_rn(__fmul_rn(row2[2*t+0].y, u), q.y);
        row2[2*t+1].x = __fmul_rn(__fmul_rn(row2[2*t+1].x, u), q.z);
        row2[2*t+1].y = __fmul_rn(__fmul_rn(row2[2*t+1].y, u), q.w);
    }

    // ---- greedy unique argmax: parallel mutual-max retirement ----------
    // R8 logic; scans 2-way interleaved (chains [0,32) and [32,64), strict
    // '>' merge with low half winning ties == linear first-max exactly).
    unsigned long long rowmask = ~0ull;   // wave-uniform (SGPR pair)
    unsigned long long colmask = ~0ull;
    int mycol  = 0;
    int rounds = 0;

    while (rowmask && rounds < 64) {
        ++rounds;

        // row side (lane = row i): best live column
        float rv0 = 0.0f, rv1 = 0.0f; int rj0 = 0, rj1 = 32;
        #pragma unroll
        for (int k = 0; k < 32; ++k) {
            {
                const int j = k;
                unsigned sm = ((colmask >> j) & 1ull) ? 0xFFFFFFFFu : 0u;
                float sv = (j & 1) ? row2[j >> 1].y : row2[j >> 1].x;
                float s  = __uint_as_float(__float_as_uint(sv) & sm);
                if (s > rv0) { rv0 = s; rj0 = j; }
            }
            {
                const int j = 32 + k;
                unsigned sm = ((colmask >> j) & 1ull) ? 0xFFFFFFFFu : 0u;
                float sv = (j & 1) ? row2[j >> 1].y : row2[j >> 1].x;
                float s  = __uint_as_float(__float_as_uint(sv) & sm);
                if (s > rv1) { rv1 = s; rj1 = j; }
            }
        }
        if (rv1 > rv0) { rv0 = rv1; rj0 = rj1; }
        const int rbj = rj0;

        // col side (lane = col j): best live row
        float cv0 = 0.0f, cv1 = 0.0f; int ci0 = 0, ci1 = 32;
        #pragma unroll
        for (int k = 0; k < 32; ++k) {
            {
                const int i = k;
                unsigned sm = ((rowmask >> i) & 1ull) ? 0xFFFFFFFFu : 0u;
                float s  = __uint_as_float(__float_as_uint(col[i]) & sm);
                if (s > cv0) { cv0 = s; ci0 = i; }
            }
            {
                const int i = 32 + k;
                unsigned sm = ((rowmask >> i) & 1ull) ? 0xFFFFFFFFu : 0u;
                float s  = __uint_as_float(__float_as_uint(col[i]) & sm);
                if (s > cv1) { cv1 = s; ci1 = i; }
            }
        }
        if (cv1 > cv0) { cv0 = cv1; ci0 = ci1; }
        const int cbi = ci0;

        // mutual check (R8 verbatim)
        int gr = __builtin_amdgcn_ds_bpermute(rbj << 2, cbi); // colArg[rbj]
        int gc = __builtin_amdgcn_ds_bpermute(cbi << 2, rbj); // rowArg[cbi]
        bool aR = (rowmask >> lane) & 1ull;
        bool aC = (colmask >> lane) & 1ull;
        bool mr = aR && (gr == lane);
        bool mc = aC && (gc == lane);
        if (mr) mycol = rbj;
        rowmask &= ~__ballot(mr);
        colmask &= ~__ballot(mc);
    }

    // ---- write hard permutation row (lane i -> row i) -----------------
    float* orow = out + (size_t)b * 4096 + lane * 64;
    #pragma unroll
    for (int t = 0; t < 16; ++t) {
        float4 q;
        q.x = (4*t+0 == mycol) ? 1.0f : 0.0f;
        q.y = (4*t+1 == mycol) ? 1.0f : 0.0f;
        q.z = (4*t+2 == mycol) ? 1.0f : 0.0f;
        q.w = (4*t+3 == mycol) ? 1.0f : 0.0f;
        ((float4*)orow)[t] = q;
    }
}

extern "C" void kernel_launch(void* const* d_in, const int* in_sizes, int n_in,
                              void* d_out, int out_size, void* d_ws, size_t ws_size,
                              hipStream_t stream) {
    const float* logits = (const float*)d_in[0];
    const float* ptemp  = (const float*)d_in[1];
    float* out = (float*)d_out;
    const int B = in_sizes[0] / 4096;   // 64*64 elements per batch
    sinkhorn_perm_kernel<<<B, 64, 0, stream>>>(logits, ptemp, out);
}

// Round 10
// 186.943 us; speedup vs baseline: 2.0497x; 1.2705x over previous
//
#include <hip/hip_runtime.h>
#include <cstdint>
#include <cstddef>

// R16 = R8 (verified 104 us, best) with ONE change: the greedy masked
// argmax scans go from 64-deep linear chains to 4 chains of 16 + ordered
// strict-'>' merge. Semantics proven exact on HW by R9 (absmax 0.0: group
// linear first-max + ascending merge, lower block wins ties == linear
// first-max over 64). R9/R13/R15 all died crossing the 128-VGPR tier
// (occ halves, ~1.7x wall) by spending +24-32 regs (double arrays,
// interleaved sides, LDS-transpose addressing). This variant is register-
// disciplined: 4 named scalar chain accumulators (no arrays), row scan and
// col scan run SEQUENTIALLY and reuse the same temps -> ~+8 regs vs R8.
// Transpose idea abandoned permanently (R13: FETCH unchanged -> re-read is
// cache-absorbed; R15: costs ~+26 VGPR). Sinkhorn, mutual-max retirement,
// prologue, epilogue: R8 byte-for-byte (bitwise-identical scores).
// Tripwire: VGPR_Count must stay <= 128.

typedef float f2 __attribute__((ext_vector_type(2)));

__device__ __forceinline__ f2 fma2(f2 a, f2 b, f2 c) {
#if defined(__has_builtin) && __has_builtin(__builtin_elementwise_fma)
    return __builtin_elementwise_fma(a, b, c);
#else
    f2 r; r.x = __builtin_fmaf(a.x, b.x, c.x); r.y = __builtin_fmaf(a.y, b.y, c.y);
    return r;
#endif
}

__global__ void __launch_bounds__(64)
__attribute__((amdgpu_waves_per_eu(1)))
sinkhorn_perm_kernel(const float* __restrict__ logits,
                     const float* __restrict__ ptemp,
                     float* __restrict__ out)
{
    __shared__ __attribute__((aligned(16))) float bufU[64];
    __shared__ __attribute__((aligned(16))) float bufV[64];

    const int b    = blockIdx.x;
    const int lane = threadIdx.x;
    const float* base = logits + (size_t)b * 4096;

    const float T    = ptemp[0] + 1e-6f;
    const float invT = 1.0f / T;          // IEEE divide (one-time)

    // ---- load row `lane`, scale by invT; pairs (4t,4t+1),(4t+2,4t+3) --
    f2 row2[32];
    {
        const float4* rp = (const float4*)(base + lane * 64);
        #pragma unroll
        for (int t = 0; t < 16; ++t) {
            float4 q = rp[t];
            row2[2*t+0].x = __fmul_rn(q.x, invT);
            row2[2*t+0].y = __fmul_rn(q.y, invT);
            row2[2*t+1].x = __fmul_rn(q.z, invT);
            row2[2*t+1].y = __fmul_rn(q.w, invT);
        }
    }

    // ---- global max over the 64x64 tile -------------------------------
    float mx = row2[0].x;
    #pragma unroll
    for (int i = 0; i < 32; ++i) { mx = fmaxf(mx, row2[i].x); mx = fmaxf(mx, row2[i].y); }
    #pragma unroll
    for (int w = 1; w <= 32; w <<= 1)
        mx = fmaxf(mx, __shfl_xor(mx, w, 64));

    // ---- x0 row copy: exp(scaled - mx) --------------------------------
    #pragma unroll
    for (int i = 0; i < 32; ++i) {
        row2[i].x = __expf(__fsub_rn(row2[i].x, mx));
        row2[i].y = __expf(__fsub_rn(row2[i].y, mx));
    }

    // ---- x0 column copy: coalesced global re-read, identical op seq ---
    float col[64];
    #pragma unroll
    for (int i = 0; i < 64; ++i) {
        float raw = base[i * 64 + lane];
        col[i] = __expf(__fsub_rn(__fmul_rn(raw, invT), mx));
    }

    // ---- sinkhorn in diag(u) * X0 * diag(v) form ----------------------
    // R8 verbatim: LDS broadcast, pk_fma pairing, rs=(A0.x+A0.y)+(A1.x+A1.y).
    const float4* bu4 = (const float4*)bufU;
    const float4* bv4 = (const float4*)bufV;

    float u = 1.0f, v = 1.0f;
    for (int it = 0; it < 30; ++it) {
        // row phase: rs_i = row_i . v
        bufV[lane] = v;
        f2 A0 = {0.f, 0.f}, A1 = {0.f, 0.f};
        #pragma unroll
        for (int t = 0; t < 16; ++t) {
            float4 q = bv4[t];
            f2 qa = { q.x, q.y };
            f2 qb = { q.z, q.w };
            A0 = fma2(row2[2*t+0], qa, A0);
            A1 = fma2(row2[2*t+1], qb, A1);
        }
        float rs = __fadd_rn(__fadd_rn(A0.x, A0.y), __fadd_rn(A1.x, A1.y));
        u = u / __fadd_rn(__fmul_rn(u, rs), 1e-8f);   // IEEE divide

        // col phase: cs_j = col_j . u  (updated u broadcast)
        bufU[lane] = u;
        A0 = (f2){0.f, 0.f}; A1 = (f2){0.f, 0.f};
        #pragma unroll
        for (int t = 0; t < 16; ++t) {
            float4 q = bu4[t];
            f2 ca = { col[4*t+0], col[4*t+1] };
            f2 cb = { col[4*t+2], col[4*t+3] };
            f2 qa = { q.x, q.y };
            f2 qb = { q.z, q.w };
            A0 = fma2(ca, qa, A0);
            A1 = fma2(cb, qb, A1);
        }
        float cs = __fadd_rn(__fadd_rn(A0.x, A0.y), __fadd_rn(A1.x, A1.y));
        v = v / __fadd_rn(__fmul_rn(v, cs), 1e-8f);
    }

    // ---- final scores in BOTH layouts: s[i][j] = (x0[i][j] * u_i) * v_j
    #pragma unroll
    for (int t = 0; t < 16; ++t) {
        float4 q = bu4[t];
        col[4*t+0] = __fmul_rn(__fmul_rn(col[4*t+0], q.x), v);
        col[4*t+1] = __fmul_rn(__fmul_rn(col[4*t+1], q.y), v);
        col[4*t+2] = __fmul_rn(__fmul_rn(col[4*t+2], q.z), v);
        col[4*t+3] = __fmul_rn(__fmul_rn(col[4*t+3], q.w), v);
    }
    bufV[lane] = v;   // final v (in-order DS within wave)
    #pragma unroll
    for (int t = 0; t < 16; ++t) {
        float4 q = bv4[t];
        row2[2*t+0].x = __fmul_rn(__fmul_rn(row2[2*t+0].x, u), q.x);
        row2[2*t+0].y = __fmul_rn(__fmul_rn(row2[2*t+0].y, u), q.y);
        row2[2*t+1].x = __fmul_rn(__fmul_rn(row2[2*t+1].x, u), q.z);
        row2[2*t+1].y = __fmul_rn(__fmul_rn(row2[2*t+1].y, u), q.w);
    }

    // ---- greedy unique argmax: parallel mutual-max retirement ----------
    // R8 retirement logic; scans = 4 chains of 16 + ordered strict-'>'
    // merge (lowest chain wins ties) == linear first-max exactly (R9-proven
    // semantics). Chains use named scalars; sides sequential, temps reused.
    unsigned long long rowmask = ~0ull;   // wave-uniform (SGPR pair)
    unsigned long long colmask = ~0ull;
    int mycol  = 0;
    int rounds = 0;

    while (rowmask && rounds < 64) {
        ++rounds;

        // row side (lane = row i): best live column
        float s0 = 0.0f, s1 = 0.0f, s2 = 0.0f, s3 = 0.0f;
        int   j0 = 0,    j1 = 16,   j2 = 32,   j3 = 48;
        #pragma unroll
        for (int k = 0; k < 16; ++k) {
            {
                const int j = k;
                unsigned sm = ((colmask >> j) & 1ull) ? 0xFFFFFFFFu : 0u;
                float sv = (j & 1) ? row2[j >> 1].y : row2[j >> 1].x;
                float s  = __uint_as_float(__float_as_uint(sv) & sm);
                if (s > s0) { s0 = s; j0 = j; }
            }
            {
                const int j = 16 + k;
                unsigned sm = ((colmask >> j) & 1ull) ? 0xFFFFFFFFu : 0u;
                float sv = (j & 1) ? row2[j >> 1].y : row2[j >> 1].x;
                float s  = __uint_as_float(__float_as_uint(sv) & sm);
                if (s > s1) { s1 = s; j1 = j; }
            }
            {
                const int j = 32 + k;
                unsigned sm = ((colmask >> j) & 1ull) ? 0xFFFFFFFFu : 0u;
                float sv = (j & 1) ? row2[j >> 1].y : row2[j >> 1].x;
                float s  = __uint_as_float(__float_as_uint(sv) & sm);
                if (s > s2) { s2 = s; j2 = j; }
            }
            {
                const int j = 48 + k;
                unsigned sm = ((colmask >> j) & 1ull) ? 0xFFFFFFFFu : 0u;
                float sv = (j & 1) ? row2[j >> 1].y : row2[j >> 1].x;
                float s  = __uint_as_float(__float_as_uint(sv) & sm);
                if (s > s3) { s3 = s; j3 = j; }
            }
        }
        if (s1 > s0) { s0 = s1; j0 = j1; }
        if (s2 > s0) { s0 = s2; j0 = j2; }
        if (s3 > s0) { s0 = s3; j0 = j3; }
        const int rbj = j0;

        // col side (lane = col j): best live row (reuses the same temps)
        s0 = 0.0f; s1 = 0.0f; s2 = 0.0f; s3 = 0.0f;
        j0 = 0;    j1 = 16;   j2 = 32;   j3 = 48;
        #pragma unroll
        for (int k = 0; k < 16; ++k) {
            {
                const int i = k;
                unsigned sm = ((rowmask >> i) & 1ull) ? 0xFFFFFFFFu : 0u;
                float s  = __uint_as_float(__float_as_uint(col[i]) & sm);
                if (s > s0) { s0 = s; j0 = i; }
            }
            {
                const int i = 16 + k;
                unsigned sm = ((rowmask >> i) & 1ull) ? 0xFFFFFFFFu : 0u;
                float s  = __uint_as_float(__float_as_uint(col[i]) & sm);
                if (s > s1) { s1 = s; j1 = i; }
            }
            {
                const int i = 32 + k;
                unsigned sm = ((rowmask >> i) & 1ull) ? 0xFFFFFFFFu : 0u;
                float s  = __uint_as_float(__float_as_uint(col[i]) & sm);
                if (s > s2) { s2 = s; j2 = i; }
            }
            {
                const int i = 48 + k;
                unsigned sm = ((rowmask >> i) & 1ull) ? 0xFFFFFFFFu : 0u;
                float s  = __uint_as_float(__float_as_uint(col[i]) & sm);
                if (s > s3) { s3 = s; j3 = i; }
            }
        }
        if (s1 > s0) { s0 = s1; j0 = j1; }
        if (s2 > s0) { s0 = s2; j0 = j2; }
        if (s3 > s0) { s0 = s3; j0 = j3; }
        const int cbi = j0;

        // mutual check (R8 verbatim)
        int gr = __builtin_amdgcn_ds_bpermute(rbj << 2, cbi); // colArg[rbj]
        int gc = __builtin_amdgcn_ds_bpermute(cbi << 2, rbj); // rowArg[cbi]
        bool aR = (rowmask >> lane) & 1ull;
        bool aC = (colmask >> lane) & 1ull;
        bool mr = aR && (gr == lane);
        bool mc = aC && (gc == lane);
        if (mr) mycol = rbj;
        rowmask &= ~__ballot(mr);
        colmask &= ~__ballot(mc);
    }

    // ---- write hard permutation row (lane i -> row i) -----------------
    float* orow = out + (size_t)b * 4096 + lane * 64;
    #pragma unroll
    for (int t = 0; t < 16; ++t) {
        float4 q;
        q.x = (4*t+0 == mycol) ? 1.0f : 0.0f;
        q.y = (4*t+1 == mycol) ? 1.0f : 0.0f;
        q.z = (4*t+2 == mycol) ? 1.0f : 0.0f;
        q.w = (4*t+3 == mycol) ? 1.0f : 0.0f;
        ((float4*)orow)[t] = q;
    }
}

extern "C" void kernel_launch(void* const* d_in, const int* in_sizes, int n_in,
                              void* d_out, int out_size, void* d_ws, size_t ws_size,
                              hipStream_t stream) {
    const float* logits = (const float*)d_in[0];
    const float* ptemp  = (const float*)d_in[1];
    float* out = (float*)d_out;
    const int B = in_sizes[0] / 4096;   // 64*64 elements per batch
    sinkhorn_perm_kernel<<<B, 64, 0, stream>>>(logits, ptemp, out);
}